// Round 2
// baseline (1240.521 us; speedup 1.0000x reference)
//
#include <hip/hip_runtime.h>
#include <hip/hip_bf16.h>
#include <math.h>

#define NTOK  8192      // B*T
#define DD    1024
#define HH    4096
#define EE    8
#define NSLOT (NTOK*2)  // total compacted (token, expert) slots = NTOK*K

typedef __attribute__((ext_vector_type(8))) short bf16x8;   // 8 bf16 (4 VGPRs)
typedef __attribute__((ext_vector_type(4))) float f32x4;

static __device__ __forceinline__ float gelu_exact(float v) {
    return 0.5f * v * (1.0f + erff(v * 0.70710678118654752f));
}

// ---------------- x -> bf16 ----------------
__global__ __launch_bounds__(256) void cvt_x_kernel(const float* __restrict__ x,
                                                    __hip_bfloat16* __restrict__ xb) {
    int i = (blockIdx.x * 256 + threadIdx.x) * 4;
    float4 v = *(const float4*)(x + i);
    __hip_bfloat162 lo = __float22bfloat162_rn(make_float2(v.x, v.y));
    __hip_bfloat162 hi = __float22bfloat162_rn(make_float2(v.z, v.w));
    *(__hip_bfloat162*)(xb + i)     = lo;
    *(__hip_bfloat162*)(xb + i + 2) = hi;
}

// ------------- W transpose+convert: src [E][R][C] f32 -> dst [E][C][R] bf16 -------------
__global__ __launch_bounds__(256) void cvt_w_t_kernel(const float* __restrict__ src,
                                                      __hip_bfloat16* __restrict__ dst,
                                                      int R, int C) {
    __shared__ float tile[32][33];
    int e = blockIdx.z;
    size_t base = (size_t)e * R * C;
    int c0 = blockIdx.x * 32, r0 = blockIdx.y * 32;
    int tx = threadIdx.x, ty = threadIdx.y;
    #pragma unroll
    for (int q = 0; q < 4; ++q)
        tile[ty + q * 8][tx] = src[base + (size_t)(r0 + ty + q * 8) * C + (c0 + tx)];
    __syncthreads();
    #pragma unroll
    for (int q = 0; q < 4; ++q)
        dst[base + (size_t)(c0 + ty + q * 8) * R + (r0 + tx)] =
            __float2bfloat16(tile[tx][ty + q * 8]);
}

// ---------------- router: logits, top-2, renorm weights, counts ----------------
__global__ __launch_bounds__(256) void router_kernel(const float* __restrict__ x,
                                                     const float* __restrict__ Wr,
                                                     int* __restrict__ topk_idx,
                                                     float* __restrict__ topk_w,
                                                     int* __restrict__ counts) {
    __shared__ float wr[DD * 9];   // stride 9: 9*l mod 32 cycles all banks -> 2-way max
    for (int i = threadIdx.x; i < DD * EE; i += 256) {
        int d = i >> 3, e = i & 7;
        wr[d * 9 + e] = Wr[i];
    }
    __syncthreads();
    int wave = threadIdx.x >> 6, lane = threadIdx.x & 63;
    int t = blockIdx.x * 4 + wave;
    const float* xr = x + (size_t)t * DD;
    float acc[EE] = {};
    for (int j = 0; j < DD / 64; ++j) {
        float v = xr[j * 64 + lane];
        int d = j * 64 + lane;
        #pragma unroll
        for (int e = 0; e < EE; ++e) acc[e] += v * wr[d * 9 + e];
    }
    #pragma unroll
    for (int off = 32; off > 0; off >>= 1)
        #pragma unroll
        for (int e = 0; e < EE; ++e) acc[e] += __shfl_xor(acc[e], off);
    if (lane == 0) {
        int e1 = 0;
        #pragma unroll
        for (int e = 1; e < EE; ++e) if (acc[e] > acc[e1]) e1 = e;
        int e2 = (e1 == 0) ? 1 : 0;
        #pragma unroll
        for (int e = 0; e < EE; ++e)
            if (e != e1 && e != e2 && acc[e] > acc[e2]) e2 = e;
        // softmax + topk + renorm  ==  softmax over the two top logits
        float w1 = 1.0f / (1.0f + expf(acc[e2] - acc[e1]));
        topk_idx[t * 2]     = e1;
        topk_idx[t * 2 + 1] = e2;
        topk_w[t * 2]       = w1;
        topk_w[t * 2 + 1]   = 1.0f - w1;
        atomicAdd(&counts[e1], 1);
        atomicAdd(&counts[e2], 1);
    }
}

// ---------------- prefix sum over 8 counts ----------------
__global__ void prefix_kernel(const int* __restrict__ counts,
                              int* __restrict__ offsets, int* __restrict__ cursors) {
    if (threadIdx.x == 0 && blockIdx.x == 0) {
        int s = 0;
        for (int e = 0; e < EE; ++e) { offsets[e] = s; cursors[e] = s; s += counts[e]; }
        offsets[EE] = s;   // == NSLOT
    }
}

// ---------------- scatter tokens into compacted per-expert buckets ----------------
__global__ __launch_bounds__(256) void scatter_kernel(const int* __restrict__ topk_idx,
                                                      const float* __restrict__ topk_w,
                                                      int* __restrict__ cursors,
                                                      int* __restrict__ btok,
                                                      float* __restrict__ bw) {
    int t = blockIdx.x * 256 + threadIdx.x;
    if (t >= NTOK) return;
    #pragma unroll
    for (int k = 0; k < 2; ++k) {
        int e = topk_idx[t * 2 + k];
        int p = atomicAdd(&cursors[e], 1);
        btok[p] = t;
        bw[p]   = topk_w[t * 2 + k];
    }
}

// ---------------- fc1: Hc[slot, n] = gelu(Xg @ W1[e] + b1[e]) for h-chunk ----------------
// 128x128 tile, BK=32, 4 waves, each wave 64x64 (4x4 MFMA 16x16x32 tiles)
// Staging: 128 rows x 32 K-cols = 8192 B/operand; 256 threads stage TWO uint4
// rows each (r and r+64) — R1 bugfix: one row/thread left rows 64..127 uninit.
__global__ __launch_bounds__(256) void fc1_kernel(
    const __hip_bfloat16* __restrict__ xb, const __hip_bfloat16* __restrict__ w1t,
    const float* __restrict__ b1, const int* __restrict__ offsets,
    const int* __restrict__ btok, __hip_bfloat16* __restrict__ hbuf,
    int h0, int Cchunk) {
    int e = blockIdx.z;
    int seg0 = offsets[e];
    int cnt  = offsets[e + 1] - seg0;
    int m0 = blockIdx.y * 128;
    if (m0 >= cnt) return;
    int n0 = h0 + blockIdx.x * 128;

    __shared__ __hip_bfloat16 As[128 * 40];  // row stride 40 bf16 (80B): 2-way banks only
    __shared__ __hip_bfloat16 Bs[128 * 40];

    int tid = threadIdx.x;
    int r = tid >> 2, cq = (tid & 3) * 8;    // r in [0,64)
    int arow0 = m0 + r, arow1 = m0 + r + 64;
    int tok0 = btok[seg0 + (arow0 < cnt ? arow0 : 0)];
    int tok1 = btok[seg0 + (arow1 < cnt ? arow1 : 0)];
    const __hip_bfloat16* ap0 = xb + (size_t)tok0 * DD + cq;
    const __hip_bfloat16* ap1 = xb + (size_t)tok1 * DD + cq;
    const __hip_bfloat16* bp0 = w1t + ((size_t)e * HH + n0 + r) * DD + cq;
    const __hip_bfloat16* bp1 = w1t + ((size_t)e * HH + n0 + r + 64) * DD + cq;

    int wv = tid >> 6, lane = tid & 63;
    int wr_ = wv >> 1, wc = wv & 1;
    int q = lane >> 4, lc = lane & 15;

    f32x4 acc[4][4] = {};

    for (int k0 = 0; k0 < DD; k0 += 32) {
        uint4 av0 = *(const uint4*)(ap0 + k0);
        uint4 av1 = *(const uint4*)(ap1 + k0);
        uint4 bv0 = *(const uint4*)(bp0 + k0);
        uint4 bv1 = *(const uint4*)(bp1 + k0);
        __syncthreads();
        *(uint4*)(As + r * 40 + cq)        = av0;
        *(uint4*)(As + (r + 64) * 40 + cq) = av1;
        *(uint4*)(Bs + r * 40 + cq)        = bv0;
        *(uint4*)(Bs + (r + 64) * 40 + cq) = bv1;
        __syncthreads();
        bf16x8 af[4], bg[4];
        #pragma unroll
        for (int i = 0; i < 4; ++i)
            af[i] = *(const bf16x8*)(As + (wr_ * 64 + i * 16 + lc) * 40 + q * 8);
        #pragma unroll
        for (int j = 0; j < 4; ++j)
            bg[j] = *(const bf16x8*)(Bs + (wc * 64 + j * 16 + lc) * 40 + q * 8);
        #pragma unroll
        for (int i = 0; i < 4; ++i)
            #pragma unroll
            for (int j = 0; j < 4; ++j)
                acc[i][j] = __builtin_amdgcn_mfma_f32_16x16x32_bf16(af[i], bg[j], acc[i][j], 0, 0, 0);
    }

    #pragma unroll
    for (int i = 0; i < 4; ++i) {
        #pragma unroll
        for (int j = 0; j < 4; ++j) {
            int col = n0 + wc * 64 + j * 16 + lc;        // global h
            float bias = b1[e * HH + col];
            #pragma unroll
            for (int rg = 0; rg < 4; ++rg) {
                int ml = wr_ * 64 + i * 16 + q * 4 + rg;  // C/D: col=lane&15, row=quad*4+reg
                if (m0 + ml < cnt) {
                    float v = acc[i][j][rg] + bias;
                    hbuf[(size_t)(seg0 + m0 + ml) * Cchunk + (col - h0)] =
                        __float2bfloat16(gelu_exact(v));
                }
            }
        }
    }
}

// ---------------- fc2: out[token] += w * (Hc @ W2[e] + b2[e]) ----------------
__global__ __launch_bounds__(256) void fc2_kernel(
    const __hip_bfloat16* __restrict__ hbuf, const __hip_bfloat16* __restrict__ w2t,
    const float* __restrict__ b2, const int* __restrict__ offsets,
    const int* __restrict__ btok, const float* __restrict__ bw,
    float* __restrict__ out, int h0, int Cchunk) {
    int e = blockIdx.z;
    int seg0 = offsets[e];
    int cnt  = offsets[e + 1] - seg0;
    int m0 = blockIdx.y * 128;
    if (m0 >= cnt) return;
    int n0 = blockIdx.x * 128;   // d cols

    __shared__ __hip_bfloat16 As[128 * 40];
    __shared__ __hip_bfloat16 Bs[128 * 40];

    int tid = threadIdx.x;
    int r = tid >> 2, cq = (tid & 3) * 8;
    int arow0 = m0 + r, arow1 = m0 + r + 64;
    int slot0 = seg0 + (arow0 < cnt ? arow0 : 0);
    int slot1 = seg0 + (arow1 < cnt ? arow1 : 0);
    const __hip_bfloat16* ap0 = hbuf + (size_t)slot0 * Cchunk + cq;
    const __hip_bfloat16* ap1 = hbuf + (size_t)slot1 * Cchunk + cq;
    const __hip_bfloat16* bp0 = w2t + ((size_t)e * DD + n0 + r) * HH + h0 + cq;
    const __hip_bfloat16* bp1 = w2t + ((size_t)e * DD + n0 + r + 64) * HH + h0 + cq;

    int wv = tid >> 6, lane = tid & 63;
    int wr_ = wv >> 1, wc = wv & 1;
    int q = lane >> 4, lc = lane & 15;

    f32x4 acc[4][4] = {};

    for (int k0 = 0; k0 < Cchunk; k0 += 32) {
        uint4 av0 = *(const uint4*)(ap0 + k0);
        uint4 av1 = *(const uint4*)(ap1 + k0);
        uint4 bv0 = *(const uint4*)(bp0 + k0);
        uint4 bv1 = *(const uint4*)(bp1 + k0);
        __syncthreads();
        *(uint4*)(As + r * 40 + cq)        = av0;
        *(uint4*)(As + (r + 64) * 40 + cq) = av1;
        *(uint4*)(Bs + r * 40 + cq)        = bv0;
        *(uint4*)(Bs + (r + 64) * 40 + cq) = bv1;
        __syncthreads();
        bf16x8 af[4], bg[4];
        #pragma unroll
        for (int i = 0; i < 4; ++i)
            af[i] = *(const bf16x8*)(As + (wr_ * 64 + i * 16 + lc) * 40 + q * 8);
        #pragma unroll
        for (int j = 0; j < 4; ++j)
            bg[j] = *(const bf16x8*)(Bs + (wc * 64 + j * 16 + lc) * 40 + q * 8);
        #pragma unroll
        for (int i = 0; i < 4; ++i)
            #pragma unroll
            for (int j = 0; j < 4; ++j)
                acc[i][j] = __builtin_amdgcn_mfma_f32_16x16x32_bf16(af[i], bg[j], acc[i][j], 0, 0, 0);
    }

    #pragma unroll
    for (int i = 0; i < 4; ++i) {
        #pragma unroll
        for (int j = 0; j < 4; ++j) {
            int col = n0 + wc * 64 + j * 16 + lc;   // d
            float bias = b2[e * DD + col];
            #pragma unroll
            for (int rg = 0; rg < 4; ++rg) {
                int ml = wr_ * 64 + i * 16 + q * 4 + rg;
                if (m0 + ml < cnt) {
                    int s = seg0 + m0 + ml;
                    int t = btok[s];
                    float w = bw[s];
                    float add = w * acc[i][j][rg];
                    if (h0 == 0) add += w * bias;   // fold b2 once
                    atomicAdd(out + (size_t)t * DD + col, add);
                }
            }
        }
    }
}

static inline size_t alignup(size_t v, size_t a) { return (v + a - 1) & ~(a - 1); }

extern "C" void kernel_launch(void* const* d_in, const int* in_sizes, int n_in,
                              void* d_out, int out_size, void* d_ws, size_t ws_size,
                              hipStream_t stream) {
    const float* x  = (const float*)d_in[0];
    const float* Wr = (const float*)d_in[1];
    const float* W1 = (const float*)d_in[2];
    const float* b1 = (const float*)d_in[3];
    const float* W2 = (const float*)d_in[4];
    const float* b2 = (const float*)d_in[5];
    float* out = (float*)d_out;

    char* p = (char*)d_ws;
    size_t off = 0;
    int* counts  = (int*)(p + off); off += 64;
    int* offsets = (int*)(p + off); off += 64;
    int* cursors = (int*)(p + off); off += 64;
    off = alignup(off, 256);
    int*   topk_idx = (int*)(p + off);   off += (size_t)NTOK * 2 * 4;
    float* topk_w   = (float*)(p + off); off += (size_t)NTOK * 2 * 4;
    int*   btok     = (int*)(p + off);   off += (size_t)NSLOT * 4;
    float* bwt      = (float*)(p + off); off += (size_t)NSLOT * 4;
    off = alignup(off, 256);
    __hip_bfloat16* xb  = (__hip_bfloat16*)(p + off); off += (size_t)NTOK * DD * 2;
    __hip_bfloat16* w1t = (__hip_bfloat16*)(p + off); off += (size_t)EE * DD * HH * 2;
    __hip_bfloat16* w2t = (__hip_bfloat16*)(p + off); off += (size_t)EE * DD * HH * 2;
    off = alignup(off, 256);
    __hip_bfloat16* hbuf = (__hip_bfloat16*)(p + off);
    size_t rem = (ws_size > off) ? (ws_size - off) : 0;
    int C = HH;                                   // h-chunk width for Hbuf
    while (C > 128 && (size_t)NSLOT * C * 2 > rem) C >>= 1;

    hipMemsetAsync(d_out, 0, (size_t)NTOK * DD * 4, stream);
    hipMemsetAsync(counts, 0, 192, stream);

    cvt_x_kernel<<<NTOK * DD / 1024, 256, 0, stream>>>(x, xb);
    cvt_w_t_kernel<<<dim3(HH / 32, DD / 32, EE), dim3(32, 8), 0, stream>>>(W1, w1t, DD, HH);
    cvt_w_t_kernel<<<dim3(DD / 32, HH / 32, EE), dim3(32, 8), 0, stream>>>(W2, w2t, HH, DD);
    router_kernel<<<NTOK / 4, 256, 0, stream>>>(x, Wr, topk_idx, topk_w, counts);
    prefix_kernel<<<1, 64, 0, stream>>>(counts, offsets, cursors);
    scatter_kernel<<<NTOK / 256, 256, 0, stream>>>(topk_idx, topk_w, cursors, btok, bwt);

    for (int h0 = 0; h0 < HH; h0 += C) {
        fc1_kernel<<<dim3(C / 128, NTOK / 128, EE), 256, 0, stream>>>(
            xb, w1t, b1, offsets, btok, hbuf, h0, C);
        fc2_kernel<<<dim3(DD / 128, NTOK / 128, EE), 256, 0, stream>>>(
            hbuf, w2t, b2, offsets, btok, bwt, out, h0, C);
    }
}

// Round 3
// 1139.105 us; speedup vs baseline: 1.0890x; 1.0890x over previous
//
#include <hip/hip_runtime.h>
#include <hip/hip_bf16.h>
#include <math.h>

#define NTOK  8192      // B*T
#define DD    1024
#define HH    4096
#define EE    8
#define NSLOT (NTOK*2)  // total compacted (token, expert) slots = NTOK*K

typedef __attribute__((ext_vector_type(8))) short bf16x8;   // 8 bf16 (4 VGPRs)
typedef __attribute__((ext_vector_type(4))) float f32x4;

static __device__ __forceinline__ float gelu_exact(float v) {
    return 0.5f * v * (1.0f + erff(v * 0.70710678118654752f));
}

// async global->LDS, 16B per lane; LDS dest is wave-uniform base + lane*16
static __device__ __forceinline__ void gload16(const void* g, void* l) {
    __builtin_amdgcn_global_load_lds(
        (const __attribute__((address_space(1))) void*)g,
        (__attribute__((address_space(3))) void*)l, 16, 0, 0);
}

// ---------------- x -> bf16 ----------------
__global__ __launch_bounds__(256) void cvt_x_kernel(const float* __restrict__ x,
                                                    __hip_bfloat16* __restrict__ xb) {
    int i = (blockIdx.x * 256 + threadIdx.x) * 4;
    float4 v = *(const float4*)(x + i);
    __hip_bfloat162 lo = __float22bfloat162_rn(make_float2(v.x, v.y));
    __hip_bfloat162 hi = __float22bfloat162_rn(make_float2(v.z, v.w));
    *(__hip_bfloat162*)(xb + i)     = lo;
    *(__hip_bfloat162*)(xb + i + 2) = hi;
}

// ------------- W transpose+convert: src [E][R][C] f32 -> dst [E][C][R] bf16 -------------
__global__ __launch_bounds__(256) void cvt_w_t_kernel(const float* __restrict__ src,
                                                      __hip_bfloat16* __restrict__ dst,
                                                      int R, int C) {
    __shared__ float tile[32][33];
    int e = blockIdx.z;
    size_t base = (size_t)e * R * C;
    int c0 = blockIdx.x * 32, r0 = blockIdx.y * 32;
    int tx = threadIdx.x, ty = threadIdx.y;
    #pragma unroll
    for (int q = 0; q < 4; ++q)
        tile[ty + q * 8][tx] = src[base + (size_t)(r0 + ty + q * 8) * C + (c0 + tx)];
    __syncthreads();
    #pragma unroll
    for (int q = 0; q < 4; ++q)
        dst[base + (size_t)(c0 + ty + q * 8) * R + (r0 + tx)] =
            __float2bfloat16(tile[tx][ty + q * 8]);
}

// ---------------- router: logits, top-2, renorm weights, counts ----------------
__global__ __launch_bounds__(256) void router_kernel(const float* __restrict__ x,
                                                     const float* __restrict__ Wr,
                                                     int* __restrict__ topk_idx,
                                                     float* __restrict__ topk_w,
                                                     int* __restrict__ counts) {
    __shared__ float wr[DD * 9];   // stride 9: cycles all banks, 2-way max
    for (int i = threadIdx.x; i < DD * EE; i += 256) {
        int d = i >> 3, e = i & 7;
        wr[d * 9 + e] = Wr[i];
    }
    __syncthreads();
    int wave = threadIdx.x >> 6, lane = threadIdx.x & 63;
    int t = blockIdx.x * 4 + wave;
    const float* xr = x + (size_t)t * DD;
    float acc[EE] = {};
    for (int j = 0; j < DD / 64; ++j) {
        float v = xr[j * 64 + lane];
        int d = j * 64 + lane;
        #pragma unroll
        for (int e = 0; e < EE; ++e) acc[e] += v * wr[d * 9 + e];
    }
    #pragma unroll
    for (int off = 32; off > 0; off >>= 1)
        #pragma unroll
        for (int e = 0; e < EE; ++e) acc[e] += __shfl_xor(acc[e], off);
    if (lane == 0) {
        int e1 = 0;
        #pragma unroll
        for (int e = 1; e < EE; ++e) if (acc[e] > acc[e1]) e1 = e;
        int e2 = (e1 == 0) ? 1 : 0;
        #pragma unroll
        for (int e = 0; e < EE; ++e)
            if (e != e1 && e != e2 && acc[e] > acc[e2]) e2 = e;
        // softmax + topk + renorm == softmax over the two top logits
        float w1 = 1.0f / (1.0f + expf(acc[e2] - acc[e1]));
        topk_idx[t * 2]     = e1;
        topk_idx[t * 2 + 1] = e2;
        topk_w[t * 2]       = w1;
        topk_w[t * 2 + 1]   = 1.0f - w1;
        atomicAdd(&counts[e1], 1);
        atomicAdd(&counts[e2], 1);
    }
}

// ---------------- prefix sum over 8 counts ----------------
__global__ void prefix_kernel(const int* __restrict__ counts,
                              int* __restrict__ offsets, int* __restrict__ cursors) {
    if (threadIdx.x == 0 && blockIdx.x == 0) {
        int s = 0;
        for (int e = 0; e < EE; ++e) { offsets[e] = s; cursors[e] = s; s += counts[e]; }
        offsets[EE] = s;   // == NSLOT
    }
}

// ---------------- scatter tokens into compacted per-expert buckets ----------------
__global__ __launch_bounds__(256) void scatter_kernel(const int* __restrict__ topk_idx,
                                                      int* __restrict__ cursors,
                                                      int* __restrict__ btok,
                                                      int* __restrict__ slot_of) {
    int t = blockIdx.x * 256 + threadIdx.x;
    if (t >= NTOK) return;
    #pragma unroll
    for (int k = 0; k < 2; ++k) {
        int e = topk_idx[t * 2 + k];
        int p = atomicAdd(&cursors[e], 1);
        btok[p] = t;
        slot_of[t * 2 + k] = p;
    }
}

// ---------------- fc1: Hc[slot, n] = gelu(Xg @ W1[e]^T-layout + b1[e]) ----------------
// m97 structure: 128x128 tile, BK=32, global_load_lds width=16, unpadded LDS.
// Each wave stages 32 A-rows + 32 B-rows per K-step (2+2 gloads of 1KB each).
__global__ __launch_bounds__(256) void fc1_kernel(
    const __hip_bfloat16* __restrict__ xb, const __hip_bfloat16* __restrict__ w1t,
    const float* __restrict__ b1g, const int* __restrict__ offsets,
    const int* __restrict__ btok, __hip_bfloat16* __restrict__ hbuf,
    int h0, int Cchunk) {
    int e = blockIdx.z;
    int seg0 = offsets[e];
    int cnt  = offsets[e + 1] - seg0;
    int m0 = blockIdx.y * 128;
    if (m0 >= cnt) return;
    int n0 = h0 + blockIdx.x * 128;

    __shared__ __align__(16) __hip_bfloat16 As[128 * 32];  // unpadded: global_load_lds req
    __shared__ __align__(16) __hip_bfloat16 Bs[128 * 32];

    int tid = threadIdx.x;
    int wv = tid >> 6, lane = tid & 63;
    int lr  = lane >> 2;      // row within 16-row group
    int lcq = lane & 3;       // 16B quarter of a 64B row

    int ra0 = wv * 32 + lr;   // staging rows for this lane
    int ra1 = ra0 + 16;
    int ga0 = m0 + ra0, ga1 = m0 + ra1;
    int tok0 = btok[seg0 + (ga0 < cnt ? ga0 : 0)];
    int tok1 = btok[seg0 + (ga1 < cnt ? ga1 : 0)];
    const __hip_bfloat16* a0 = xb + (size_t)tok0 * DD + lcq * 8;
    const __hip_bfloat16* a1 = xb + (size_t)tok1 * DD + lcq * 8;
    const __hip_bfloat16* b0 = w1t + ((size_t)e * HH + n0 + ra0) * DD + lcq * 8;
    const __hip_bfloat16* b1p = w1t + ((size_t)e * HH + n0 + ra1) * DD + lcq * 8;
    __hip_bfloat16* lA0 = As + (wv * 32) * 32;       // wave-uniform LDS bases
    __hip_bfloat16* lA1 = As + (wv * 32 + 16) * 32;
    __hip_bfloat16* lB0 = Bs + (wv * 32) * 32;
    __hip_bfloat16* lB1 = Bs + (wv * 32 + 16) * 32;

    int wr_ = wv >> 1, wc = wv & 1;
    int q = lane >> 4, lc = lane & 15;

    f32x4 acc[4][4] = {};

    for (int k0 = 0; k0 < DD; k0 += 32) {
        gload16(a0 + k0, lA0);
        gload16(a1 + k0, lA1);
        gload16(b0 + k0, lB0);
        gload16(b1p + k0, lB1);
        __syncthreads();   // drains vmcnt + barrier
        bf16x8 af[4], bg[4];
        #pragma unroll
        for (int i = 0; i < 4; ++i)
            af[i] = *(const bf16x8*)(As + (wr_ * 64 + i * 16 + lc) * 32 + q * 8);
        #pragma unroll
        for (int j = 0; j < 4; ++j)
            bg[j] = *(const bf16x8*)(Bs + (wc * 64 + j * 16 + lc) * 32 + q * 8);
        #pragma unroll
        for (int i = 0; i < 4; ++i)
            #pragma unroll
            for (int j = 0; j < 4; ++j)
                acc[i][j] = __builtin_amdgcn_mfma_f32_16x16x32_bf16(af[i], bg[j], acc[i][j], 0, 0, 0);
        __syncthreads();   // compute done before next overwrite
    }

    #pragma unroll
    for (int i = 0; i < 4; ++i) {
        #pragma unroll
        for (int j = 0; j < 4; ++j) {
            int col = n0 + wc * 64 + j * 16 + lc;        // global h
            float bias = b1g[e * HH + col];
            #pragma unroll
            for (int rg = 0; rg < 4; ++rg) {
                int ml = wr_ * 64 + i * 16 + q * 4 + rg;  // C/D: col=lane&15, row=quad*4+reg
                if (m0 + ml < cnt) {
                    float v = acc[i][j][rg] + bias;
                    hbuf[(size_t)(seg0 + m0 + ml) * Cchunk + (col - h0)] =
                        __float2bfloat16(gelu_exact(v));
                }
            }
        }
    }
}

// ---------------- fc2: ybuf[slot] (+)= Hc @ W2[e]^T-layout ----------------
// No atomics: each (slot,d) owned by exactly one block; combine folds weights+b2.
__global__ __launch_bounds__(256) void fc2_kernel(
    const __hip_bfloat16* __restrict__ hbuf, const __hip_bfloat16* __restrict__ w2t,
    const int* __restrict__ offsets, float* __restrict__ ybuf,
    int h0, int Cchunk) {
    int e = blockIdx.z;
    int seg0 = offsets[e];
    int cnt  = offsets[e + 1] - seg0;
    int m0 = blockIdx.y * 128;
    if (m0 >= cnt) return;
    int n0 = blockIdx.x * 128;   // d cols

    __shared__ __align__(16) __hip_bfloat16 As[128 * 32];
    __shared__ __align__(16) __hip_bfloat16 Bs[128 * 32];

    int tid = threadIdx.x;
    int wv = tid >> 6, lane = tid & 63;
    int lr  = lane >> 2;
    int lcq = lane & 3;

    int ra0 = wv * 32 + lr;
    int ra1 = ra0 + 16;
    int ga0 = m0 + ra0, ga1 = m0 + ra1;
    int slot0 = seg0 + (ga0 < cnt ? ga0 : 0);
    int slot1 = seg0 + (ga1 < cnt ? ga1 : 0);
    const __hip_bfloat16* a0 = hbuf + (size_t)slot0 * Cchunk + lcq * 8;
    const __hip_bfloat16* a1 = hbuf + (size_t)slot1 * Cchunk + lcq * 8;
    const __hip_bfloat16* b0 = w2t + ((size_t)e * DD + n0 + ra0) * HH + h0 + lcq * 8;
    const __hip_bfloat16* b1p = w2t + ((size_t)e * DD + n0 + ra1) * HH + h0 + lcq * 8;
    __hip_bfloat16* lA0 = As + (wv * 32) * 32;
    __hip_bfloat16* lA1 = As + (wv * 32 + 16) * 32;
    __hip_bfloat16* lB0 = Bs + (wv * 32) * 32;
    __hip_bfloat16* lB1 = Bs + (wv * 32 + 16) * 32;

    int wr_ = wv >> 1, wc = wv & 1;
    int q = lane >> 4, lc = lane & 15;

    f32x4 acc[4][4] = {};

    for (int k0 = 0; k0 < Cchunk; k0 += 32) {
        gload16(a0 + k0, lA0);
        gload16(a1 + k0, lA1);
        gload16(b0 + k0, lB0);
        gload16(b1p + k0, lB1);
        __syncthreads();
        bf16x8 af[4], bg[4];
        #pragma unroll
        for (int i = 0; i < 4; ++i)
            af[i] = *(const bf16x8*)(As + (wr_ * 64 + i * 16 + lc) * 32 + q * 8);
        #pragma unroll
        for (int j = 0; j < 4; ++j)
            bg[j] = *(const bf16x8*)(Bs + (wc * 64 + j * 16 + lc) * 32 + q * 8);
        #pragma unroll
        for (int i = 0; i < 4; ++i)
            #pragma unroll
            for (int j = 0; j < 4; ++j)
                acc[i][j] = __builtin_amdgcn_mfma_f32_16x16x32_bf16(af[i], bg[j], acc[i][j], 0, 0, 0);
        __syncthreads();
    }

    #pragma unroll
    for (int i = 0; i < 4; ++i) {
        #pragma unroll
        for (int j = 0; j < 4; ++j) {
            int col = n0 + wc * 64 + j * 16 + lc;   // d
            #pragma unroll
            for (int rg = 0; rg < 4; ++rg) {
                int ml = wr_ * 64 + i * 16 + q * 4 + rg;
                if (m0 + ml < cnt) {
                    size_t yi = (size_t)(seg0 + m0 + ml) * DD + col;
                    float v = acc[i][j][rg];
                    ybuf[yi] = (h0 == 0) ? v : (ybuf[yi] + v);
                }
            }
        }
    }
}

// ---------------- combine: out[t] = sum_k w_k * (y[slot_k] + b2[e_k]) ----------------
__global__ __launch_bounds__(256) void combine_kernel(
    const float* __restrict__ ybuf, const float* __restrict__ b2,
    const int* __restrict__ topk_idx, const float* __restrict__ topk_w,
    const int* __restrict__ slot_of, float* __restrict__ out) {
    int idx = blockIdx.x * 256 + threadIdx.x;   // NTOK*DD/4 total
    int t  = idx >> 8;                           // DD/4 = 256 per token
    int d4 = (idx & 255) * 4;
    int e0 = topk_idx[t * 2], e1 = topk_idx[t * 2 + 1];
    float w0 = topk_w[t * 2], w1 = topk_w[t * 2 + 1];
    int s0 = slot_of[t * 2], s1 = slot_of[t * 2 + 1];
    float4 y0 = *(const float4*)(ybuf + (size_t)s0 * DD + d4);
    float4 y1 = *(const float4*)(ybuf + (size_t)s1 * DD + d4);
    float4 c0 = *(const float4*)(b2 + e0 * DD + d4);
    float4 c1 = *(const float4*)(b2 + e1 * DD + d4);
    float4 o;
    o.x = w0 * (y0.x + c0.x) + w1 * (y1.x + c1.x);
    o.y = w0 * (y0.y + c0.y) + w1 * (y1.y + c1.y);
    o.z = w0 * (y0.z + c0.z) + w1 * (y1.z + c1.z);
    o.w = w0 * (y0.w + c0.w) + w1 * (y1.w + c1.w);
    *(float4*)(out + (size_t)t * DD + d4) = o;
}

static inline size_t alignup(size_t v, size_t a) { return (v + a - 1) & ~(a - 1); }

extern "C" void kernel_launch(void* const* d_in, const int* in_sizes, int n_in,
                              void* d_out, int out_size, void* d_ws, size_t ws_size,
                              hipStream_t stream) {
    const float* x  = (const float*)d_in[0];
    const float* Wr = (const float*)d_in[1];
    const float* W1 = (const float*)d_in[2];
    const float* b1 = (const float*)d_in[3];
    const float* W2 = (const float*)d_in[4];
    const float* b2 = (const float*)d_in[5];
    float* out = (float*)d_out;

    char* p = (char*)d_ws;
    size_t off = 0;
    int* counts  = (int*)(p + off); off += 64;
    int* offsets = (int*)(p + off); off += 64;
    int* cursors = (int*)(p + off); off += 64;
    off = alignup(off, 256);
    int*   topk_idx = (int*)(p + off);   off += (size_t)NTOK * 2 * 4;
    float* topk_w   = (float*)(p + off); off += (size_t)NTOK * 2 * 4;
    int*   btok     = (int*)(p + off);   off += (size_t)NSLOT * 4;
    int*   slot_of  = (int*)(p + off);   off += (size_t)NTOK * 2 * 4;
    off = alignup(off, 256);
    __hip_bfloat16* xb  = (__hip_bfloat16*)(p + off); off += (size_t)NTOK * DD * 2;
    __hip_bfloat16* w1t = (__hip_bfloat16*)(p + off); off += (size_t)EE * DD * HH * 2;
    __hip_bfloat16* w2t = (__hip_bfloat16*)(p + off); off += (size_t)EE * DD * HH * 2;
    float* ybuf = (float*)(p + off);                  off += (size_t)NSLOT * DD * 4;
    off = alignup(off, 256);
    __hip_bfloat16* hbuf = (__hip_bfloat16*)(p + off);
    size_t rem = (ws_size > off) ? (ws_size - off) : 0;
    int C = HH;                                   // h-chunk width for Hbuf
    while (C > 128 && (size_t)NSLOT * C * 2 > rem) C >>= 1;

    hipMemsetAsync(counts, 0, 192, stream);

    cvt_x_kernel<<<NTOK * DD / 1024, 256, 0, stream>>>(x, xb);
    cvt_w_t_kernel<<<dim3(HH / 32, DD / 32, EE), dim3(32, 8), 0, stream>>>(W1, w1t, DD, HH);
    cvt_w_t_kernel<<<dim3(DD / 32, HH / 32, EE), dim3(32, 8), 0, stream>>>(W2, w2t, HH, DD);
    router_kernel<<<NTOK / 4, 256, 0, stream>>>(x, Wr, topk_idx, topk_w, counts);
    prefix_kernel<<<1, 64, 0, stream>>>(counts, offsets, cursors);
    scatter_kernel<<<NTOK / 256, 256, 0, stream>>>(topk_idx, cursors, btok, slot_of);

    for (int h0 = 0; h0 < HH; h0 += C) {
        fc1_kernel<<<dim3(C / 128, NTOK / 128, EE), 256, 0, stream>>>(
            xb, w1t, b1, offsets, btok, hbuf, h0, C);
        fc2_kernel<<<dim3(DD / 128, NTOK / 128, EE), 256, 0, stream>>>(
            hbuf, w2t, offsets, ybuf, h0, C);
    }
    combine_kernel<<<NTOK * DD / 4 / 256, 256, 0, stream>>>(
        ybuf, b2, topk_idx, topk_w, slot_of, out);
}